// Round 2
// baseline (1025.232 us; speedup 1.0000x reference)
//
#include <hip/hip_runtime.h>
#include <cstdint>
#include <cstddef>

typedef _Float16 half8 __attribute__((ext_vector_type(8)));
typedef _Float16 half4v __attribute__((ext_vector_type(4)));
typedef float f32x4 __attribute__((ext_vector_type(4)));

#define NCOL 512   // 2*M interleaved (re,im)
#define KY 256     // 2*N interleaved

__device__ __forceinline__ float shrinkf(float v, float eta) {
  float a = fabsf(v) - eta;           // LAMBD = 1.0
  return a > 0.0f ? copysignf(a, v) : 0.0f;
}

// ---------- table builders ----------
// Wa[n=2p+c][k=2q+d], 512 x 256: realified A
__global__ void build_wa(const float* __restrict__ A, _Float16* __restrict__ Wa) {
  int idx = blockIdx.x * 256 + threadIdx.x;     // 131072
  int n = idx >> 8, k = idx & 255;
  int p = n >> 1, c = n & 1, q = k >> 1, d = k & 1;
  const float* A0 = A;                // (256,128)
  const float* A1 = A + 256 * 128;
  float v;
  if (c == 0) v = (d == 0) ? A0[p * 128 + q] : -A1[p * 128 + q];
  else        v = (d == 0) ? A1[p * 128 + q] :  A0[p * 128 + q];
  Wa[idx] = (_Float16)v;
}

// Wc_t = realify(I - g_t * B), 10 tables of 512 x 512
__global__ void build_wc(const float* __restrict__ B, const float* __restrict__ gammas,
                         _Float16* __restrict__ Wc) {
  int idx = blockIdx.x * 256 + threadIdx.x;     // 2,621,440
  int t = idx >> 18;
  int r = idx & 262143;
  int n = r >> 9, k = r & 511;
  int p = n >> 1, c = n & 1, q = k >> 1, d = k & 1;
  float g = gammas[t + 1];
  const float* B0 = B;                // (256,256)
  const float* B1 = B + 256 * 256;
  float eye = (p == q) ? 1.0f : 0.0f;
  float v;
  if (c == 0) v = (d == 0) ? (eye - g * B0[p * 256 + q]) : ( g * B1[p * 256 + q]);
  else        v = (d == 0) ? (     - g * B1[p * 256 + q]) : (eye - g * B0[p * 256 + q]);
  Wc[idx] = (_Float16)v;
}

// ---------- fused LISTA chain ----------
// Block = 64 batch rows. 4 waves, wave w owns features [w*128, w*128+128).
// MFMA operands swapped: A = weights (features x K), B = x (batch x K).
// D: row(in-reg quad*4+r) = feature, col(lane&15) = batch
//   -> iteration writeback = contiguous 4 halves (ds_write_b64)
//   -> final store = contiguous 4 floats (global_store_dwordx4)
// x lives in LDS [64][512] fp16, 16B-chunk XOR swizzle (chunk ^= batch&7):
//   b128 reads 2-way (free), b64 writes at BW floor.
// Wc fragments read straight from global (L2-resident: 512KB/table shared
// by all blocks on the XCD). Ay kept in 64 VGPRs (packed fp16).
__global__ __launch_bounds__(256, 2) void lista_fused(
    const float* __restrict__ y,
    const _Float16* __restrict__ Wa,
    const _Float16* __restrict__ Wc,
    float* __restrict__ out,
    const float* __restrict__ gammas,
    const float* __restrict__ etas) {
  __shared__ __align__(16) _Float16 xlds[64 * 512];   // 64 KB

  const int tid  = threadIdx.x;
  const int l16  = tid & 15;
  const int quad = (tid >> 4) & 3;
  const int wave = tid >> 6;          // 0..3 feature slice
  const int l7   = l16 & 7;
  const int b0   = blockIdx.x << 6;   // batch base
  const int fb   = wave << 7;         // feature base
  const int fc   = fb >> 3;           // feature base in 8-half chunks (=wave*16)

  f32x4 acc[8][4];
#pragma unroll
  for (int i = 0; i < 8; ++i)
#pragma unroll
    for (int j = 0; j < 4; ++j) acc[i][j] = {0.f, 0.f, 0.f, 0.f};

  // ---- prologue: acc = Ay tile = Wa(features,K) @ y^T(K,batch), K=256 ----
  for (int kt = 0; kt < 4; ++kt) {
#pragma unroll
    for (int ks = 0; ks < 2; ++ks) {
      const int k0 = kt * 64 + ks * 32 + quad * 8;
      half8 bf[4];
#pragma unroll
      for (int j = 0; j < 4; ++j) {
        const float* yp = y + (size_t)(b0 + j * 16 + l16) * KY + k0;
        f32x4 a = *(const f32x4*)yp;
        f32x4 b = *(const f32x4*)(yp + 4);
        half8 h;
        h[0] = (_Float16)a.x; h[1] = (_Float16)a.y;
        h[2] = (_Float16)a.z; h[3] = (_Float16)a.w;
        h[4] = (_Float16)b.x; h[5] = (_Float16)b.y;
        h[6] = (_Float16)b.z; h[7] = (_Float16)b.w;
        bf[j] = h;
      }
#pragma unroll
      for (int ih = 0; ih < 2; ++ih) {
        half8 af[4];
#pragma unroll
        for (int i = 0; i < 4; ++i)
          af[i] = *(const half8*)(Wa + (size_t)(fb + (ih * 4 + i) * 16 + l16) * KY + k0);
#pragma unroll
        for (int i = 0; i < 4; ++i)
#pragma unroll
          for (int j = 0; j < 4; ++j)
            acc[ih * 4 + i][j] = __builtin_amdgcn_mfma_f32_16x16x32_f16(
                af[i], bf[j], acc[ih * 4 + i][j], 0, 0, 0);
      }
    }
  }

  // capture Ay (raw, fp16-packed) and write x0 = shrink(g0*Ay, eta0)
  const float g0 = gammas[0], e0 = etas[0];
  half4v ayv[8][4];
#pragma unroll
  for (int i = 0; i < 8; ++i) {
    const int cw = ((fc + i * 2 + (quad >> 1)) ^ l7) * 8 + (quad & 1) * 4;
#pragma unroll
    for (int j = 0; j < 4; ++j) {
      f32x4 v = acc[i][j];
      half4v a4 = {(_Float16)v.x, (_Float16)v.y, (_Float16)v.z, (_Float16)v.w};
      ayv[i][j] = a4;
      half4v x0 = {(_Float16)shrinkf(g0 * v.x, e0), (_Float16)shrinkf(g0 * v.y, e0),
                   (_Float16)shrinkf(g0 * v.z, e0), (_Float16)shrinkf(g0 * v.w, e0)};
      *(half4v*)(xlds + (j * 16 + l16) * NCOL + cw) = x0;
    }
  }

  // ---- main loop: x = shrink((I-gB)x + g*Ay), t = 1..10 ----
  for (int t = 1; t <= 10; ++t) {
    __syncthreads();                              // x writes visible
    const float g   = gammas[t];
    const float eta = etas[t];
    const _Float16* W = Wc + (size_t)(t - 1) * (512 * 512);

#pragma unroll
    for (int i = 0; i < 8; ++i)
#pragma unroll
      for (int j = 0; j < 4; ++j) {
        half4v a4 = ayv[i][j];
        acc[i][j] = {g * (float)a4[0], g * (float)a4[1],
                     g * (float)a4[2], g * (float)a4[3]};
      }

    for (int kt = 0; kt < 8; ++kt) {
#pragma unroll
      for (int ks = 0; ks < 2; ++ks) {
        half8 bf[4];
#pragma unroll
        for (int j = 0; j < 4; ++j)
          bf[j] = *(const half8*)(xlds + (j * 16 + l16) * NCOL + kt * 64 +
                                  ((ks * 4 + quad) ^ l7) * 8);
        const size_t wk = (size_t)(kt * 64 + ks * 32 + quad * 8);
#pragma unroll
        for (int ih = 0; ih < 2; ++ih) {
          half8 af[4];
#pragma unroll
          for (int i = 0; i < 4; ++i)
            af[i] = *(const half8*)(W + (size_t)(fb + (ih * 4 + i) * 16 + l16) * NCOL + wk);
#pragma unroll
          for (int i = 0; i < 4; ++i)
#pragma unroll
            for (int j = 0; j < 4; ++j)
              acc[ih * 4 + i][j] = __builtin_amdgcn_mfma_f32_16x16x32_f16(
                  af[i], bf[j], acc[ih * 4 + i][j], 0, 0, 0);
        }
      }
    }

    __syncthreads();                              // all reads of x done
    if (t < 10) {
#pragma unroll
      for (int i = 0; i < 8; ++i) {
        const int cw = ((fc + i * 2 + (quad >> 1)) ^ l7) * 8 + (quad & 1) * 4;
#pragma unroll
        for (int j = 0; j < 4; ++j) {
          f32x4 v = acc[i][j];
          half4v xn = {(_Float16)shrinkf(v.x, eta), (_Float16)shrinkf(v.y, eta),
                       (_Float16)shrinkf(v.z, eta), (_Float16)shrinkf(v.w, eta)};
          *(half4v*)(xlds + (j * 16 + l16) * NCOL + cw) = xn;
        }
      }
    } else {
#pragma unroll
      for (int i = 0; i < 8; ++i)
#pragma unroll
        for (int j = 0; j < 4; ++j) {
          f32x4 v = acc[i][j];
          f32x4 o = {shrinkf(v.x, eta), shrinkf(v.y, eta),
                     shrinkf(v.z, eta), shrinkf(v.w, eta)};
          *(f32x4*)(out + (size_t)(b0 + j * 16 + l16) * NCOL + fb + i * 16 + quad * 4) = o;
        }
    }
  }
}

extern "C" void kernel_launch(void* const* d_in, const int* in_sizes, int n_in,
                              void* d_out, int out_size, void* d_ws, size_t ws_size,
                              hipStream_t stream) {
  const float* y      = (const float*)d_in[0];
  const float* A      = (const float*)d_in[1];
  const float* B      = (const float*)d_in[2];
  const float* etas   = (const float*)d_in[3];
  const float* gammas = (const float*)d_in[4];

  char* ws = (char*)d_ws;
  _Float16* Wa = (_Float16*)ws;                       // 512*256*2   = 256 KB
  _Float16* Wc = (_Float16*)(ws + 262144);            // 10*512*512*2 = 5 MB

  hipLaunchKernelGGL(build_wa, dim3(512), dim3(256), 0, stream, A, Wa);
  hipLaunchKernelGGL(build_wc, dim3(10240), dim3(256), 0, stream, B, gammas, Wc);
  hipLaunchKernelGGL(lista_fused, dim3(1024), dim3(256), 0, stream,
                     y, Wa, Wc, (float*)d_out, gammas, etas);
}